// Round 2
// baseline (356.825 us; speedup 1.0000x reference)
//
#include <hip/hip_runtime.h>

// Output-centric fused max-unpool, round 2: mirror the proven-fast fill kernel.
//
// Round-1 post-mortem: restructuring input-centric -> output-centric moved
// dur_us only 347->336, so whatever caps the kernel is COMMON to both versions.
// Two shared properties differ from the harness's own fillBufferAligned
// (measured 6.5 TB/s on this chip): (1) we used nontemporal stores, the fill
// uses plain stores; (2) each wave wrote only 1 KiB then hit s_endpgm (vmcnt
// drain), so per-wave MLP was ~1 outstanding store. This version:
//   - plain (cached) output stores, NT kept only on read-once val/idx loads;
//   - 4 output quads per thread at stride G = NQ/4. G is exactly 128 output
//     rows, so (oh|ow) parity is identical across a thread's 4 segments:
//     the writer/loader role stays wave-uniform, every stream stays a linear
//     coalesced sweep, and loader waves issue all 8 loads before any compare.
//
// Semantics unchanged: canonical idx quad -> store v in place; otherwise zero
// the quad and atomicAdd-scatter (reference duplicate-sum), never taken for
// the bench's canonical input. Traffic floor: 64 MB val + 64 MB idx reads +
// 256 MB out writes = 384 MB.
//
// Geometry: H=W=256, C=256, OH=OW=512.
//   output quads NQ = 512*512*64 = 16,777,216; G = NQ/4 = 4,194,304 (128 rows)
//   input quads: (h*256+w)*64 + c4; +128 output rows -> +64 pooled rows
//     -> input-quad stride GIN = 64*256*64 = 1,048,576.

typedef float  f32x4 __attribute__((ext_vector_type(4)));
typedef int    i32x4 __attribute__((ext_vector_type(4)));

__global__ __launch_bounds__(256) void unpool_oc4_kernel(
    const float* __restrict__ val,
    const int*   __restrict__ idx,
    float*       __restrict__ out)
{
    constexpr int G   = 1 << 22;  // 4,194,304 output quads per segment
    constexpr int GIN = 1 << 20;  // matching input-quad segment stride

    const int tid = blockIdx.x * blockDim.x + threadIdx.x;  // [0, G)

    f32x4* o = reinterpret_cast<f32x4*>(out);
    const f32x4 z = (f32x4)(0.f);

    const int c4  = tid & 63;          // channel quad within pixel (C/4 = 64)
    const int ow  = (tid >> 6) & 511;  // output column (segment-invariant)
    const int oh0 = tid >> 15;         // output row of segment 0 (+128 per seg)

    // Wave-uniform role, invariant across all 4 segments.
    if ((oh0 | ow) & 1) {
        // 3/4 of waves: four independent contiguous 1 KiB/wave write streams.
        #pragma unroll
        for (int k = 0; k < 4; ++k)
            o[tid + k * G] = z;
        return;
    }

    // Canonical target of pooled (h,w) = (oh/2, ow/2) in each segment.
    const int qin0 = ((oh0 >> 1) << 14) + ((ow >> 1) << 6) + c4;
    const f32x4* vq = reinterpret_cast<const f32x4*>(val);
    const i32x4* iq = reinterpret_cast<const i32x4*>(idx);

    // Issue all 8 loads up front (fully unrolled -> registers, deep MLP).
    f32x4 v[4];
    i32x4 id[4];
    #pragma unroll
    for (int k = 0; k < 4; ++k) {
        v[k]  = __builtin_nontemporal_load(vq + qin0 + k * GIN);
        id[k] = __builtin_nontemporal_load(iq + qin0 + k * GIN);
    }

    #pragma unroll
    for (int k = 0; k < 4; ++k) {
        const int q = tid + k * G;
        const int p = q << 2;  // expected canonical flat float index (< 2^26)
        if (__builtin_expect(id[k].x == p     && id[k].y == p + 1 &&
                             id[k].z == p + 2 && id[k].w == p + 3, 1)) {
            o[q] = v[k];       // canonical fast path
        } else {
            o[q] = z;          // zero the quad, scatter per reference semantics
            atomicAdd(out + id[k].x, v[k].x);
            atomicAdd(out + id[k].y, v[k].y);
            atomicAdd(out + id[k].z, v[k].z);
            atomicAdd(out + id[k].w, v[k].w);
        }
    }
}

extern "C" void kernel_launch(void* const* d_in, const int* in_sizes, int n_in,
                              void* d_out, int out_size, void* d_ws, size_t ws_size,
                              hipStream_t stream) {
    const float* val = (const float*)d_in[0];
    const int*   idx = (const int*)d_in[1];
    float* out = (float*)d_out;

    const int n       = in_sizes[0];  // 16,777,216 pooled elements = NQ quads
    const int threads = n / 4;        // 4 quads per thread = 4,194,304 threads
    const int block   = 256;
    const int grid    = threads / block;  // 16,384 blocks
    unpool_oc4_kernel<<<grid, block, 0, stream>>>(val, idx, out);
}

// Round 3
// 335.324 us; speedup vs baseline: 1.0641x; 1.0641x over previous
//
#include <hip/hip_runtime.h>

// Output-centric fused max-unpool, round 3: single-variable ablation.
// EXACTLY round-1's kernel (best so far, kernel-attributable ~131us) with ONE
// change: output stores are PLAIN (cached) instead of nontemporal.
//
// Rationale: the harness's own fillBufferAligned sustains 6.5 TB/s with plain
// stores; both our ~3 TB/s kernels used NT stores for the 256 MB output (2/3
// of total traffic). Hypothesis: NT no-allocate stores bypass L2's streaming
// write-combine path and drain to HBM at a much lower rate. Round-2 bundled
// this test with a 64MiB-power-of-2-stride segmentation (likely L2-set /
// channel aliasing) and regressed -- un-confounding here.
//
// NT is KEPT on val/idx loads (read-once, no reuse -> skip L2 pollution).
//
// Mapping (unchanged from r1): one thread per OUTPUT c-quad; wave lanes cover
// c4=0..63 of one (oh,ow) pixel so the role branch is wave-uniform:
//   (oh|ow) odd  -> pure zero-store wave (3/4 of waves);
//   both even    -> canonical target of pooled (h,w): load val/idx quads
//                   (linear streams), verify, store v; non-canonical falls
//                   back to zero + atomicAdd (reference duplicate-sum).
// All three streams are monotone linear sweeps. Traffic = 384 MB floor.
//
// Geometry: H=W=256, C=256, OH=OW=512. NQ = 512*512*64 = 16,777,216.

typedef float  f32x4 __attribute__((ext_vector_type(4)));
typedef int    i32x4 __attribute__((ext_vector_type(4)));

__global__ __launch_bounds__(256) void unpool_oc_plainst_kernel(
    const float* __restrict__ val,
    const int*   __restrict__ idx,
    float*       __restrict__ out,
    int nq)
{
    const int tid = blockIdx.x * blockDim.x + threadIdx.x;
    if (tid >= nq) return;

    f32x4* o = reinterpret_cast<f32x4*>(out);
    const f32x4 z = (f32x4)(0.f);

    const int ow = (tid >> 6) & 511;  // output column
    const int oh = tid >> 15;         // output row

    // Wave-uniform role: all 64 lanes of a wave share (oh, ow).
    if ((oh | ow) & 1) {
        o[tid] = z;                   // plain cached streaming store
        return;
    }

    // (oh, ow) both even: canonical target of pooled pixel (h, w).
    const int c4  = tid & 63;
    const int qin = ((oh >> 1) << 14) + ((ow >> 1) << 6) + c4;
    const f32x4 v  = __builtin_nontemporal_load(reinterpret_cast<const f32x4*>(val) + qin);
    const i32x4 id = __builtin_nontemporal_load(reinterpret_cast<const i32x4*>(idx) + qin);

    const int p = tid << 2;  // expected canonical flat float index (< 2^26)
    if (__builtin_expect(id.x == p && id.y == p + 1 && id.z == p + 2 && id.w == p + 3, 1)) {
        o[tid] = v;          // canonical fast path (plain store)
    } else {
        o[tid] = z;          // zero the quad, scatter per reference semantics
        atomicAdd(out + id.x, v.x);
        atomicAdd(out + id.y, v.y);
        atomicAdd(out + id.z, v.z);
        atomicAdd(out + id.w, v.w);
    }
}

extern "C" void kernel_launch(void* const* d_in, const int* in_sizes, int n_in,
                              void* d_out, int out_size, void* d_ws, size_t ws_size,
                              hipStream_t stream) {
    const float* val = (const float*)d_in[0];
    const int*   idx = (const int*)d_in[1];
    float* out = (float*)d_out;

    const int n  = in_sizes[0];   // 16,777,216 pooled elements
    const int nq = n;             // output quads
    const int block = 256;
    const int grid  = (nq + block - 1) / block;  // 65,536 blocks
    unpool_oc_plainst_kernel<<<grid, block, 0, stream>>>(val, idx, out, nq);
}